// Round 16
// baseline (304.978 us; speedup 1.0000x reference)
//
#include <hip/hip_runtime.h>
#include <hip/hip_bf16.h>

#define SEQ    2048
#define DMODEL 512
#define NH     8
#define QBLK   256   /* 8 waves x 32 q-rows */
#define KVB    128   /* two 64-key sub-tiles per barrier interval */
#define NT2    (SEQ / KVB)

#if __has_builtin(__builtin_amdgcn_exp2f)
#define EXPFN(x) __builtin_amdgcn_exp2f(x)
#define QSCALE 0.18033688011112042f   /* 0.125 * log2(e) */
#else
#define EXPFN(x) __expf(x)
#define QSCALE 0.125f
#endif

typedef __attribute__((ext_vector_type(8)))  short     bf16x8;
typedef __attribute__((ext_vector_type(4)))  float     f32x4;
typedef __attribute__((ext_vector_type(16))) float     f32x16;
typedef __attribute__((ext_vector_type(2)))  int       i32x2;

#define MFMA32(A, B, C) __builtin_amdgcn_mfma_f32_32x32x16_bf16(A, B, C, 0, 0, 0)

__device__ __forceinline__ unsigned short f2bf(float f) {
  union { float f; unsigned u; } x; x.f = f;
  return (unsigned short)((x.u + 0x7FFFu + ((x.u >> 16) & 1u)) >> 16);
}

__device__ __forceinline__ int cvtpk(float lo, float hi) {
  int r;
  asm("v_cvt_pk_bf16_f32 %0, %1, %2" : "=v"(r) : "v"(lo), "v"(hi));
  return r;
}

__device__ __forceinline__ i32x2 plswap(int a, int b) {
#if __has_builtin(__builtin_amdgcn_permlane32_swap)
  return __builtin_amdgcn_permlane32_swap(a, b, false, false);
#else
  int a2 = __shfl_xor(a, 32), b2 = __shfl_xor(b, 32);
  int hi = (threadIdx.x >> 5) & 1;
  i32x2 r; r.x = hi ? b2 : a; r.y = hi ? b : a2; return r;
#endif
}

__device__ __forceinline__ void gload16(const void* g, void* l) {
  __builtin_amdgcn_global_load_lds(
      (const __attribute__((address_space(1))) void*)g,
      (__attribute__((address_space(3))) void*)l, 16, 0, 0);
}

// ---------------------------------------------------------------------------
// Per-64-key-tile layout (K and V^T): 8KB = 32 LDS rows x 256B. Row r'=r&31
// holds keys r' and r'+32; 16B slot = (((r>>5)<<3)+g) ^ (r&15). Conflict-free.
// A 128-key KVB tile is two consecutive 8KB sub-tiles.
// ---------------------------------------------------------------------------
__global__ void prep_kv(const float* __restrict__ K, const float* __restrict__ V,
                        unsigned short* __restrict__ kb, unsigned short* __restrict__ vb) {
  if (blockIdx.x < 2048) {
    int gid = blockIdx.x * 256 + threadIdx.x;
    int g  = gid & 7;
    int s  = (gid >> 3) & (SEQ - 1);
    int bh = gid >> 14;
    int b = bh >> 3, h = bh & 7;
    const float* src = K + ((size_t)(b * SEQ + s) * DMODEL) + h * 64 + (g << 3);
    float4 a = ((const float4*)src)[0];
    float4 c = ((const float4*)src)[1];
    bf16x8 w;
    w[0] = (short)f2bf(a.x); w[1] = (short)f2bf(a.y);
    w[2] = (short)f2bf(a.z); w[3] = (short)f2bf(a.w);
    w[4] = (short)f2bf(c.x); w[5] = (short)f2bf(c.y);
    w[6] = (short)f2bf(c.z); w[7] = (short)f2bf(c.w);
    int r = s & 63;
    int slot = ((((r >> 5) << 3) + g) ^ (r & 15));
    unsigned short* dst = kb + ((size_t)bh * SEQ + (s & ~63)) * 64
                             + ((r & 31) << 7) + (slot << 3);
    *(bf16x8*)dst = w;
  } else {
    int bt = blockIdx.x - 2048;     // bh*32 + tile64
    int bh = bt >> 5, tile = bt & 31;
    int b = bh >> 3, h = bh & 7;
    int t  = threadIdx.x;
    int d  = t & 63;
    int kg = t >> 6;
    const float* src = V + ((size_t)(b * SEQ + tile * 64 + kg * 16) * DMODEL) + h * 64 + d;
    float v[16];
#pragma unroll
    for (int j = 0; j < 16; ++j) v[j] = src[(size_t)j * DMODEL];
    bf16x8 lo, hi8;
#pragma unroll
    for (int j = 0; j < 8; ++j) { lo[j] = (short)f2bf(v[j]); hi8[j] = (short)f2bf(v[8 + j]); }
    unsigned short* base = vb + ((size_t)bt << 12);
    int g0 = kg << 1, g1 = (kg << 1) | 1;
    int rb = (((d >> 5) << 3));
    int s0 = ((rb + g0) ^ (d & 15));
    int s1 = ((rb + g1) ^ (d & 15));
    unsigned short* row = base + ((d & 31) << 7);
    *(bf16x8*)(row + (s0 << 3)) = lo;
    *(bf16x8*)(row + (s1 << 3)) = hi8;
  }
}

// ---------------------------- main attention --------------------------------
// R12 structure (known-good): 8-wave block, 256 q-rows, KVB=128 double-buffer
// (64 KB LDS), fixed-max softmax (raw exp2; scale cancels in O/l).
__global__ __launch_bounds__(512, 2)
void fa_fwd(const float* __restrict__ Q, const unsigned short* __restrict__ Kb,
            const unsigned short* __restrict__ Vb, float* __restrict__ O) {
  __shared__ unsigned short kt[2][KVB * 64];   // 2 x 16 KB
  __shared__ unsigned short vt[2][64 * KVB];   // 2 x 16 KB

  const int tid = threadIdx.x;
  const int wv  = tid >> 6;      // 0..7
  const int ln  = tid & 63;
  const int l31 = ln & 31;
  const int hi  = ln >> 5;

  // XCD-chunked swizzle (256 blocks, 32 per XCD -> 4 heads per XCD L2)
  const int orig = blockIdx.x;
  const int wgid = (orig & 7) * 32 + (orig >> 3);
  const int bh = wgid >> 3;
  const int qt = wgid & 7;
  const int b = bh >> 3, h = bh & 7;

  const float* Qh = Q + (size_t)b * SEQ * DMODEL + (size_t)h * 64;
  float*       Oh = O + (size_t)b * SEQ * DMODEL + (size_t)h * 64;
  const unsigned short* Kh = Kb + (size_t)bh * SEQ * 64;
  const unsigned short* Vh = Vb + (size_t)bh * SEQ * 64;

  const int q = qt * QBLK + wv * 32 + l31;

  // ---- Q fragments: lane holds Q[q][16t+8hi+j], j=0..7 ----
  bf16x8 qf[4];
  {
    const float* qp = Qh + (size_t)q * DMODEL + (hi << 3);
#pragma unroll
    for (int t = 0; t < 4; ++t) {
      float4 a = *(const float4*)(qp + 16 * t);
      float4 c = *(const float4*)(qp + 16 * t + 4);
      bf16x8 w;
      w[0] = (short)f2bf(a.x * QSCALE); w[1] = (short)f2bf(a.y * QSCALE);
      w[2] = (short)f2bf(a.z * QSCALE); w[3] = (short)f2bf(a.w * QSCALE);
      w[4] = (short)f2bf(c.x * QSCALE); w[5] = (short)f2bf(c.y * QSCALE);
      w[6] = (short)f2bf(c.z * QSCALE); w[7] = (short)f2bf(c.w * QSCALE);
      qf[t] = w;
    }
  }

  const int rowb = l31 << 7;
  int ca[4], cb[4];
#pragma unroll
  for (int t = 0; t < 4; ++t) {
    int g = 2 * t + hi;
    ca[t] = rowb + (((g)     ^ (l31 & 15)) << 3);   // sub-tile rows 0..31
    cb[t] = rowb + (((8 + g) ^ (l31 & 15)) << 3);   // sub-tile rows 32..63
  }

  f32x16 o0 = {}, o1 = {};
  float l = 0.f;

  // stage a 128-key tile: 32 KB total; 8 waves x 4 gload_lds (1KB chunks)
#define STAGE(T2, B)                                                       \
  do {                                                                     \
    const char* gk = (const char*)(Kh + (size_t)(T2) * KVB * 64);          \
    const char* gv = (const char*)(Vh + (size_t)(T2) * KVB * 64);          \
    char* lk = (char*)&kt[(B)][0];                                         \
    char* lv = (char*)&vt[(B)][0];                                         \
    gload16(gk + (((wv)     * 64 + ln) << 4), lk + ((wv)     << 10));      \
    gload16(gk + (((wv + 8) * 64 + ln) << 4), lk + ((wv + 8) << 10));      \
    gload16(gv + (((wv)     * 64 + ln) << 4), lv + ((wv)     << 10));      \
    gload16(gv + (((wv + 8) * 64 + ln) << 4), lv + ((wv + 8) << 10));      \
  } while (0)

  // QK^T over one 64-key sub-tile
  auto qk64 = [&](const unsigned short* ktb, int base, f32x16& s0, f32x16& s1) {
    f32x16 u0 = {}, u1 = {};
#pragma unroll
    for (int ks = 0; ks < 4; ++ks) {
      bf16x8 k0 = *(const bf16x8*)&ktb[base + ca[ks]];
      bf16x8 k1 = *(const bf16x8*)&ktb[base + cb[ks]];
      __builtin_amdgcn_s_setprio(1);
      u0 = MFMA32(k0, qf[ks], u0);
      u1 = MFMA32(k1, qf[ks], u1);
      __builtin_amdgcn_s_setprio(0);
    }
    s0 = u0; s1 = u1;
  };

  // softmax (fixed-max, raw exp2) + PV over one 64-key sub-tile
  auto smpv64 = [&](f32x16& s0, f32x16& s1, const unsigned short* vtb, int base) {
#pragma unroll
    for (int ks = 0; ks < 4; ++ks) {
      float e[8];
#pragma unroll
      for (int j = 0; j < 8; ++j) {
        float sv = (ks < 2) ? s0[(ks & 1) * 8 + j] : s1[(ks & 1) * 8 + j];
        e[j] = EXPFN(sv);
      }
      l += ((e[0] + e[1]) + (e[2] + e[3])) + ((e[4] + e[5]) + (e[6] + e[7]));
      i32x2 r0 = plswap(cvtpk(e[0], e[1]), cvtpk(e[4], e[5]));
      i32x2 r1 = plswap(cvtpk(e[2], e[3]), cvtpk(e[6], e[7]));
      union { int i[4]; bf16x8 v; } pa;
      pa.i[0] = r0.x; pa.i[1] = r1.x; pa.i[2] = r0.y; pa.i[3] = r1.y;

      bf16x8 v0 = *(const bf16x8*)&vtb[base + ca[ks]];
      bf16x8 v1 = *(const bf16x8*)&vtb[base + cb[ks]];
      __builtin_amdgcn_s_setprio(1);
      o0 = MFMA32(v0, pa.v, o0);
      o1 = MFMA32(v1, pa.v, o1);
      __builtin_amdgcn_s_setprio(0);
    }
  };

  // tile body: two independent sub-tiles
  auto tilec = [&](const unsigned short* ktb, const unsigned short* vtb) {
    f32x16 sA0, sA1, sB0, sB1;
    qk64(ktb, 0,    sA0, sA1);
    qk64(ktb, 4096, sB0, sB1);
    smpv64(sA0, sA1, vtb, 0);
    smpv64(sB0, sB1, vtb, 4096);
  };

  STAGE(0, 0);
  __syncthreads();
#pragma unroll
  for (int t = 0; t < NT2; t += 2) {
    STAGE(t + 1, 1);                  // t+1 <= 15, always valid
    tilec(kt[0], vt[0]);
    __syncthreads();
    if (t + 2 < NT2) STAGE(t + 2, 0);
    tilec(kt[1], vt[1]);
    __syncthreads();
  }

  // ---- epilogue (nontemporal O stores: O never re-read; keep L2 for K/V) ----
  l += __shfl_xor(l, 32);
  float rinv = 1.0f / l;
  float* op = Oh + (size_t)q * DMODEL;
#pragma unroll
  for (int r4 = 0; r4 < 4; ++r4) {
    f32x4 w0, w1;
    w0.x = o0[4 * r4 + 0] * rinv; w0.y = o0[4 * r4 + 1] * rinv;
    w0.z = o0[4 * r4 + 2] * rinv; w0.w = o0[4 * r4 + 3] * rinv;
    w1.x = o1[4 * r4 + 0] * rinv; w1.y = o1[4 * r4 + 1] * rinv;
    w1.z = o1[4 * r4 + 2] * rinv; w1.w = o1[4 * r4 + 3] * rinv;
#if __has_builtin(__builtin_nontemporal_store)
    __builtin_nontemporal_store(w0, (f32x4*)(op + 8 * r4 + 4 * hi));
    __builtin_nontemporal_store(w1, (f32x4*)(op + 32 + 8 * r4 + 4 * hi));
#else
    *(f32x4*)(op + 8 * r4 + 4 * hi)      = w0;
    *(f32x4*)(op + 32 + 8 * r4 + 4 * hi) = w1;
#endif
  }
}

extern "C" void kernel_launch(void* const* d_in, const int* in_sizes, int n_in,
                              void* d_out, int out_size, void* d_ws, size_t ws_size,
                              hipStream_t stream) {
  const float* Q = (const float*)d_in[0];
  const float* K = (const float*)d_in[1];
  const float* V = (const float*)d_in[2];
  float* O = (float*)d_out;
  unsigned short* kb = (unsigned short*)d_ws;
  unsigned short* vb = kb + (size_t)32 * SEQ * 64;
  prep_kv<<<3072, 256, 0, stream>>>(K, V, kb, vb);
  fa_fwd<<<256, 512, 0, stream>>>(Q, kb, vb, O);
}

// Round 17
// 63.154 us; speedup vs baseline: 4.8291x; 4.8291x over previous
//
#include <hip/hip_runtime.h>
#include <hip/hip_bf16.h>

#define SEQ    2048
#define DMODEL 512
#define NH     8
#define QBLK   256   /* 8 waves x 32 q-rows */
#define KVB    128   /* two 64-key sub-tiles per barrier interval */
#define NT2    (SEQ / KVB)

#if __has_builtin(__builtin_amdgcn_exp2f)
#define EXPFN(x) __builtin_amdgcn_exp2f(x)
#define QSCALE 0.18033688011112042f   /* 0.125 * log2(e) */
#else
#define EXPFN(x) __expf(x)
#define QSCALE 0.125f
#endif

typedef __attribute__((ext_vector_type(8)))  short     bf16x8;
typedef __attribute__((ext_vector_type(4)))  float     f32x4;
typedef __attribute__((ext_vector_type(16))) float     f32x16;
typedef __attribute__((ext_vector_type(2)))  int       i32x2;

#define MFMA32(A, B, C) __builtin_amdgcn_mfma_f32_32x32x16_bf16(A, B, C, 0, 0, 0)

__device__ __forceinline__ unsigned short f2bf(float f) {
  union { float f; unsigned u; } x; x.f = f;
  return (unsigned short)((x.u + 0x7FFFu + ((x.u >> 16) & 1u)) >> 16);
}

__device__ __forceinline__ int cvtpk(float lo, float hi) {
  int r;
  asm("v_cvt_pk_bf16_f32 %0, %1, %2" : "=v"(r) : "v"(lo), "v"(hi));
  return r;
}

__device__ __forceinline__ i32x2 plswap(int a, int b) {
#if __has_builtin(__builtin_amdgcn_permlane32_swap)
  return __builtin_amdgcn_permlane32_swap(a, b, false, false);
#else
  int a2 = __shfl_xor(a, 32), b2 = __shfl_xor(b, 32);
  int hi = (threadIdx.x >> 5) & 1;
  i32x2 r; r.x = hi ? b2 : a; r.y = hi ? b : a2; return r;
#endif
}

__device__ __forceinline__ void gload16(const void* g, void* l) {
  __builtin_amdgcn_global_load_lds(
      (const __attribute__((address_space(1))) void*)g,
      (__attribute__((address_space(3))) void*)l, 16, 0, 0);
}

// ---------------------------------------------------------------------------
// Per-64-key-tile layout (K and V^T): 8KB = 32 LDS rows x 256B. Row r'=r&31
// holds keys r' and r'+32; 16B slot = (((r>>5)<<3)+g) ^ (r&15). Conflict-free.
// A 128-key KVB tile is two consecutive 8KB sub-tiles.
// ---------------------------------------------------------------------------
__global__ void prep_kv(const float* __restrict__ K, const float* __restrict__ V,
                        unsigned short* __restrict__ kb, unsigned short* __restrict__ vb) {
  if (blockIdx.x < 2048) {
    int gid = blockIdx.x * 256 + threadIdx.x;
    int g  = gid & 7;
    int s  = (gid >> 3) & (SEQ - 1);
    int bh = gid >> 14;
    int b = bh >> 3, h = bh & 7;
    const float* src = K + ((size_t)(b * SEQ + s) * DMODEL) + h * 64 + (g << 3);
    float4 a = ((const float4*)src)[0];
    float4 c = ((const float4*)src)[1];
    bf16x8 w;
    w[0] = (short)f2bf(a.x); w[1] = (short)f2bf(a.y);
    w[2] = (short)f2bf(a.z); w[3] = (short)f2bf(a.w);
    w[4] = (short)f2bf(c.x); w[5] = (short)f2bf(c.y);
    w[6] = (short)f2bf(c.z); w[7] = (short)f2bf(c.w);
    int r = s & 63;
    int slot = ((((r >> 5) << 3) + g) ^ (r & 15));
    unsigned short* dst = kb + ((size_t)bh * SEQ + (s & ~63)) * 64
                             + ((r & 31) << 7) + (slot << 3);
    *(bf16x8*)dst = w;
  } else {
    int bt = blockIdx.x - 2048;     // bh*32 + tile64
    int bh = bt >> 5, tile = bt & 31;
    int b = bh >> 3, h = bh & 7;
    int t  = threadIdx.x;
    int d  = t & 63;
    int kg = t >> 6;
    const float* src = V + ((size_t)(b * SEQ + tile * 64 + kg * 16) * DMODEL) + h * 64 + d;
    float v[16];
#pragma unroll
    for (int j = 0; j < 16; ++j) v[j] = src[(size_t)j * DMODEL];
    bf16x8 lo, hi8;
#pragma unroll
    for (int j = 0; j < 8; ++j) { lo[j] = (short)f2bf(v[j]); hi8[j] = (short)f2bf(v[8 + j]); }
    unsigned short* base = vb + ((size_t)bt << 12);
    int g0 = kg << 1, g1 = (kg << 1) | 1;
    int rb = (((d >> 5) << 3));
    int s0 = ((rb + g0) ^ (d & 15));
    int s1 = ((rb + g1) ^ (d & 15));
    unsigned short* row = base + ((d & 31) << 7);
    *(bf16x8*)(row + (s0 << 3)) = lo;
    *(bf16x8*)(row + (s1 << 3)) = hi8;
  }
}

// ---------------------------- main attention --------------------------------
// R12 structure (known-good): 8-wave block, 256 q-rows, KVB=128 double-buffer
// (64 KB LDS), fixed-max softmax (raw exp2; scale cancels in O/l).
// NOTE: main loop NOT unrolled -- full unroll spills the 4 live f32x16
// S-states to scratch (R16: 437 MB scratch writes, 5x slowdown).
__global__ __launch_bounds__(512, 2)
void fa_fwd(const float* __restrict__ Q, const unsigned short* __restrict__ Kb,
            const unsigned short* __restrict__ Vb, float* __restrict__ O) {
  __shared__ unsigned short kt[2][KVB * 64];   // 2 x 16 KB
  __shared__ unsigned short vt[2][64 * KVB];   // 2 x 16 KB

  const int tid = threadIdx.x;
  const int wv  = tid >> 6;      // 0..7
  const int ln  = tid & 63;
  const int l31 = ln & 31;
  const int hi  = ln >> 5;

  // XCD-chunked swizzle (256 blocks, 32 per XCD -> 4 heads per XCD L2)
  const int orig = blockIdx.x;
  const int wgid = (orig & 7) * 32 + (orig >> 3);
  const int bh = wgid >> 3;
  const int qt = wgid & 7;
  const int b = bh >> 3, h = bh & 7;

  const float* Qh = Q + (size_t)b * SEQ * DMODEL + (size_t)h * 64;
  float*       Oh = O + (size_t)b * SEQ * DMODEL + (size_t)h * 64;
  const unsigned short* Kh = Kb + (size_t)bh * SEQ * 64;
  const unsigned short* Vh = Vb + (size_t)bh * SEQ * 64;

  const int q = qt * QBLK + wv * 32 + l31;

  // ---- Q fragments: lane holds Q[q][16t+8hi+j], j=0..7 ----
  bf16x8 qf[4];
  {
    const float* qp = Qh + (size_t)q * DMODEL + (hi << 3);
#pragma unroll
    for (int t = 0; t < 4; ++t) {
      float4 a = *(const float4*)(qp + 16 * t);
      float4 c = *(const float4*)(qp + 16 * t + 4);
      bf16x8 w;
      w[0] = (short)f2bf(a.x * QSCALE); w[1] = (short)f2bf(a.y * QSCALE);
      w[2] = (short)f2bf(a.z * QSCALE); w[3] = (short)f2bf(a.w * QSCALE);
      w[4] = (short)f2bf(c.x * QSCALE); w[5] = (short)f2bf(c.y * QSCALE);
      w[6] = (short)f2bf(c.z * QSCALE); w[7] = (short)f2bf(c.w * QSCALE);
      qf[t] = w;
    }
  }

  const int rowb = l31 << 7;
  int ca[4], cb[4];
#pragma unroll
  for (int t = 0; t < 4; ++t) {
    int g = 2 * t + hi;
    ca[t] = rowb + (((g)     ^ (l31 & 15)) << 3);   // sub-tile rows 0..31
    cb[t] = rowb + (((8 + g) ^ (l31 & 15)) << 3);   // sub-tile rows 32..63
  }

  f32x16 o0 = {}, o1 = {};
  float l = 0.f;

  // stage a 128-key tile: 32 KB total; 8 waves x 4 gload_lds (1KB chunks)
#define STAGE(T2, B)                                                       \
  do {                                                                     \
    const char* gk = (const char*)(Kh + (size_t)(T2) * KVB * 64);          \
    const char* gv = (const char*)(Vh + (size_t)(T2) * KVB * 64);          \
    char* lk = (char*)&kt[(B)][0];                                         \
    char* lv = (char*)&vt[(B)][0];                                         \
    gload16(gk + (((wv)     * 64 + ln) << 4), lk + ((wv)     << 10));      \
    gload16(gk + (((wv + 8) * 64 + ln) << 4), lk + ((wv + 8) << 10));      \
    gload16(gv + (((wv)     * 64 + ln) << 4), lv + ((wv)     << 10));      \
    gload16(gv + (((wv + 8) * 64 + ln) << 4), lv + ((wv + 8) << 10));      \
  } while (0)

  // QK^T over one 64-key sub-tile
  auto qk64 = [&](const unsigned short* ktb, int base, f32x16& s0, f32x16& s1) {
    f32x16 u0 = {}, u1 = {};
#pragma unroll
    for (int ks = 0; ks < 4; ++ks) {
      bf16x8 k0 = *(const bf16x8*)&ktb[base + ca[ks]];
      bf16x8 k1 = *(const bf16x8*)&ktb[base + cb[ks]];
      __builtin_amdgcn_s_setprio(1);
      u0 = MFMA32(k0, qf[ks], u0);
      u1 = MFMA32(k1, qf[ks], u1);
      __builtin_amdgcn_s_setprio(0);
    }
    s0 = u0; s1 = u1;
  };

  // softmax (fixed-max, raw exp2) + PV over one 64-key sub-tile
  auto smpv64 = [&](f32x16& s0, f32x16& s1, const unsigned short* vtb, int base) {
#pragma unroll
    for (int ks = 0; ks < 4; ++ks) {
      float e[8];
#pragma unroll
      for (int j = 0; j < 8; ++j) {
        float sv = (ks < 2) ? s0[(ks & 1) * 8 + j] : s1[(ks & 1) * 8 + j];
        e[j] = EXPFN(sv);
      }
      l += ((e[0] + e[1]) + (e[2] + e[3])) + ((e[4] + e[5]) + (e[6] + e[7]));
      i32x2 r0 = plswap(cvtpk(e[0], e[1]), cvtpk(e[4], e[5]));
      i32x2 r1 = plswap(cvtpk(e[2], e[3]), cvtpk(e[6], e[7]));
      union { int i[4]; bf16x8 v; } pa;
      pa.i[0] = r0.x; pa.i[1] = r1.x; pa.i[2] = r0.y; pa.i[3] = r1.y;

      bf16x8 v0 = *(const bf16x8*)&vtb[base + ca[ks]];
      bf16x8 v1 = *(const bf16x8*)&vtb[base + cb[ks]];
      __builtin_amdgcn_s_setprio(1);
      o0 = MFMA32(v0, pa.v, o0);
      o1 = MFMA32(v1, pa.v, o1);
      __builtin_amdgcn_s_setprio(0);
    }
  };

  // tile body: two independent sub-tiles
  auto tilec = [&](const unsigned short* ktb, const unsigned short* vtb) {
    f32x16 sA0, sA1, sB0, sB1;
    qk64(ktb, 0,    sA0, sA1);
    qk64(ktb, 4096, sB0, sB1);
    smpv64(sA0, sA1, vtb, 0);
    smpv64(sB0, sB1, vtb, 4096);
  };

  STAGE(0, 0);
  __syncthreads();
  for (int t = 0; t < NT2; t += 2) {
    STAGE(t + 1, 1);                  // t+1 <= 15, always valid
    tilec(kt[0], vt[0]);
    __syncthreads();
    if (t + 2 < NT2) STAGE(t + 2, 0);
    tilec(kt[1], vt[1]);
    __syncthreads();
  }

  // ---- epilogue (nontemporal O stores: O never re-read; keep L2 for K/V) ----
  l += __shfl_xor(l, 32);
  float rinv = 1.0f / l;
  float* op = Oh + (size_t)q * DMODEL;
#pragma unroll
  for (int r4 = 0; r4 < 4; ++r4) {
    f32x4 w0, w1;
    w0.x = o0[4 * r4 + 0] * rinv; w0.y = o0[4 * r4 + 1] * rinv;
    w0.z = o0[4 * r4 + 2] * rinv; w0.w = o0[4 * r4 + 3] * rinv;
    w1.x = o1[4 * r4 + 0] * rinv; w1.y = o1[4 * r4 + 1] * rinv;
    w1.z = o1[4 * r4 + 2] * rinv; w1.w = o1[4 * r4 + 3] * rinv;
#if __has_builtin(__builtin_nontemporal_store)
    __builtin_nontemporal_store(w0, (f32x4*)(op + 8 * r4 + 4 * hi));
    __builtin_nontemporal_store(w1, (f32x4*)(op + 32 + 8 * r4 + 4 * hi));
#else
    *(f32x4*)(op + 8 * r4 + 4 * hi)      = w0;
    *(f32x4*)(op + 32 + 8 * r4 + 4 * hi) = w1;
#endif
  }
}

extern "C" void kernel_launch(void* const* d_in, const int* in_sizes, int n_in,
                              void* d_out, int out_size, void* d_ws, size_t ws_size,
                              hipStream_t stream) {
  const float* Q = (const float*)d_in[0];
  const float* K = (const float*)d_in[1];
  const float* V = (const float*)d_in[2];
  float* O = (float*)d_out;
  unsigned short* kb = (unsigned short*)d_ws;
  unsigned short* vb = kb + (size_t)32 * SEQ * 64;
  prep_kv<<<3072, 256, 0, stream>>>(K, V, kb, vb);
  fa_fwd<<<256, 512, 0, stream>>>(Q, kb, vb, O);
}

// Round 18
// 55.800 us; speedup vs baseline: 5.4656x; 1.1318x over previous
//
#include <hip/hip_runtime.h>
#include <hip/hip_bf16.h>

#define SEQ    2048
#define DMODEL 512
#define NH     8
#define QBLK   256   /* 8 waves x 32 q-rows */
#define KVB    128   /* two 64-key sub-tiles per barrier interval */
#define NT2    (SEQ / KVB)

#if __has_builtin(__builtin_amdgcn_exp2f)
#define EXPFN(x) __builtin_amdgcn_exp2f(x)
#define QSCALE 0.18033688011112042f   /* 0.125 * log2(e) */
#else
#define EXPFN(x) __expf(x)
#define QSCALE 0.125f
#endif

typedef __attribute__((ext_vector_type(8)))  short     bf16x8;
typedef __attribute__((ext_vector_type(16))) float     f32x16;
typedef __attribute__((ext_vector_type(2)))  int       i32x2;

#define MFMA32(A, B, C) __builtin_amdgcn_mfma_f32_32x32x16_bf16(A, B, C, 0, 0, 0)

__device__ __forceinline__ unsigned short f2bf(float f) {
  union { float f; unsigned u; } x; x.f = f;
  return (unsigned short)((x.u + 0x7FFFu + ((x.u >> 16) & 1u)) >> 16);
}

__device__ __forceinline__ int cvtpk(float lo, float hi) {
  int r;
  asm("v_cvt_pk_bf16_f32 %0, %1, %2" : "=v"(r) : "v"(lo), "v"(hi));
  return r;
}

__device__ __forceinline__ i32x2 plswap(int a, int b) {
#if __has_builtin(__builtin_amdgcn_permlane32_swap)
  return __builtin_amdgcn_permlane32_swap(a, b, false, false);
#else
  int a2 = __shfl_xor(a, 32), b2 = __shfl_xor(b, 32);
  int hi = (threadIdx.x >> 5) & 1;
  i32x2 r; r.x = hi ? b2 : a; r.y = hi ? b : a2; return r;
#endif
}

__device__ __forceinline__ void gload16(const void* g, void* l) {
  __builtin_amdgcn_global_load_lds(
      (const __attribute__((address_space(1))) void*)g,
      (__attribute__((address_space(3))) void*)l, 16, 0, 0);
}

// ---------------------------------------------------------------------------
// Per-64-key-tile layout (K and V^T): 8KB = 32 LDS rows x 256B. Row r'=r&31
// holds keys r' and r'+32; 16B slot = (((r>>5)<<3)+g) ^ (r&15). Conflict-free.
// A 128-key KVB tile is two consecutive 8KB sub-tiles.
// ---------------------------------------------------------------------------
__global__ void prep_kv(const float* __restrict__ K, const float* __restrict__ V,
                        unsigned short* __restrict__ kb, unsigned short* __restrict__ vb) {
  if (blockIdx.x < 2048) {
    int gid = blockIdx.x * 256 + threadIdx.x;
    int g  = gid & 7;
    int s  = (gid >> 3) & (SEQ - 1);
    int bh = gid >> 14;
    int b = bh >> 3, h = bh & 7;
    const float* src = K + ((size_t)(b * SEQ + s) * DMODEL) + h * 64 + (g << 3);
    float4 a = ((const float4*)src)[0];
    float4 c = ((const float4*)src)[1];
    bf16x8 w;
    w[0] = (short)f2bf(a.x); w[1] = (short)f2bf(a.y);
    w[2] = (short)f2bf(a.z); w[3] = (short)f2bf(a.w);
    w[4] = (short)f2bf(c.x); w[5] = (short)f2bf(c.y);
    w[6] = (short)f2bf(c.z); w[7] = (short)f2bf(c.w);
    int r = s & 63;
    int slot = ((((r >> 5) << 3) + g) ^ (r & 15));
    unsigned short* dst = kb + ((size_t)bh * SEQ + (s & ~63)) * 64
                             + ((r & 31) << 7) + (slot << 3);
    *(bf16x8*)dst = w;
  } else {
    int bt = blockIdx.x - 2048;     // bh*32 + tile64
    int bh = bt >> 5, tile = bt & 31;
    int b = bh >> 3, h = bh & 7;
    int t  = threadIdx.x;
    int d  = t & 63;
    int kg = t >> 6;
    const float* src = V + ((size_t)(b * SEQ + tile * 64 + kg * 16) * DMODEL) + h * 64 + d;
    float v[16];
#pragma unroll
    for (int j = 0; j < 16; ++j) v[j] = src[(size_t)j * DMODEL];
    bf16x8 lo, hi8;
#pragma unroll
    for (int j = 0; j < 8; ++j) { lo[j] = (short)f2bf(v[j]); hi8[j] = (short)f2bf(v[8 + j]); }
    unsigned short* base = vb + ((size_t)bt << 12);
    int g0 = kg << 1, g1 = (kg << 1) | 1;
    int rb = (((d >> 5) << 3));
    int s0 = ((rb + g0) ^ (d & 15));
    int s1 = ((rb + g1) ^ (d & 15));
    unsigned short* row = base + ((d & 31) << 7);
    *(bf16x8*)(row + (s0 << 3)) = lo;
    *(bf16x8*)(row + (s1 << 3)) = hi8;
  }
}

// ---------------------------- main attention --------------------------------
// R12 structure (session best): 8-wave block, 256 q-rows, KVB=128
// double-buffer (64 KB LDS), fixed-max softmax (raw exp2; scale cancels).
// Main loop NOT unrolled (R16: unroll spills S-states to scratch, 5x).
// Plain O stores (R17: nontemporal 16B stores break write-combining, +70%
// write traffic, -10% perf).
__global__ __launch_bounds__(512, 2)
void fa_fwd(const float* __restrict__ Q, const unsigned short* __restrict__ Kb,
            const unsigned short* __restrict__ Vb, float* __restrict__ O) {
  __shared__ unsigned short kt[2][KVB * 64];   // 2 x 16 KB
  __shared__ unsigned short vt[2][64 * KVB];   // 2 x 16 KB

  const int tid = threadIdx.x;
  const int wv  = tid >> 6;      // 0..7
  const int ln  = tid & 63;
  const int l31 = ln & 31;
  const int hi  = ln >> 5;

  // XCD-chunked swizzle (256 blocks, 32 per XCD -> 4 heads per XCD L2)
  const int orig = blockIdx.x;
  const int wgid = (orig & 7) * 32 + (orig >> 3);
  const int bh = wgid >> 3;
  const int qt = wgid & 7;
  const int b = bh >> 3, h = bh & 7;

  const float* Qh = Q + (size_t)b * SEQ * DMODEL + (size_t)h * 64;
  float*       Oh = O + (size_t)b * SEQ * DMODEL + (size_t)h * 64;
  const unsigned short* Kh = Kb + (size_t)bh * SEQ * 64;
  const unsigned short* Vh = Vb + (size_t)bh * SEQ * 64;

  const int q = qt * QBLK + wv * 32 + l31;

  // ---- Q fragments: lane holds Q[q][16t+8hi+j], j=0..7 ----
  bf16x8 qf[4];
  {
    const float* qp = Qh + (size_t)q * DMODEL + (hi << 3);
#pragma unroll
    for (int t = 0; t < 4; ++t) {
      float4 a = *(const float4*)(qp + 16 * t);
      float4 c = *(const float4*)(qp + 16 * t + 4);
      bf16x8 w;
      w[0] = (short)f2bf(a.x * QSCALE); w[1] = (short)f2bf(a.y * QSCALE);
      w[2] = (short)f2bf(a.z * QSCALE); w[3] = (short)f2bf(a.w * QSCALE);
      w[4] = (short)f2bf(c.x * QSCALE); w[5] = (short)f2bf(c.y * QSCALE);
      w[6] = (short)f2bf(c.z * QSCALE); w[7] = (short)f2bf(c.w * QSCALE);
      qf[t] = w;
    }
  }

  const int rowb = l31 << 7;
  int ca[4], cb[4];
#pragma unroll
  for (int t = 0; t < 4; ++t) {
    int g = 2 * t + hi;
    ca[t] = rowb + (((g)     ^ (l31 & 15)) << 3);   // sub-tile rows 0..31
    cb[t] = rowb + (((8 + g) ^ (l31 & 15)) << 3);   // sub-tile rows 32..63
  }

  f32x16 o0 = {}, o1 = {};
  float l = 0.f;

  // stage a 128-key tile: 32 KB total; 8 waves x 4 gload_lds (1KB chunks)
#define STAGE(T2, B)                                                       \
  do {                                                                     \
    const char* gk = (const char*)(Kh + (size_t)(T2) * KVB * 64);          \
    const char* gv = (const char*)(Vh + (size_t)(T2) * KVB * 64);          \
    char* lk = (char*)&kt[(B)][0];                                         \
    char* lv = (char*)&vt[(B)][0];                                         \
    gload16(gk + (((wv)     * 64 + ln) << 4), lk + ((wv)     << 10));      \
    gload16(gk + (((wv + 8) * 64 + ln) << 4), lk + ((wv + 8) << 10));      \
    gload16(gv + (((wv)     * 64 + ln) << 4), lv + ((wv)     << 10));      \
    gload16(gv + (((wv + 8) * 64 + ln) << 4), lv + ((wv + 8) << 10));      \
  } while (0)

  // QK^T over one 64-key sub-tile
  auto qk64 = [&](const unsigned short* ktb, int base, f32x16& s0, f32x16& s1) {
    f32x16 u0 = {}, u1 = {};
#pragma unroll
    for (int ks = 0; ks < 4; ++ks) {
      bf16x8 k0 = *(const bf16x8*)&ktb[base + ca[ks]];
      bf16x8 k1 = *(const bf16x8*)&ktb[base + cb[ks]];
      __builtin_amdgcn_s_setprio(1);
      u0 = MFMA32(k0, qf[ks], u0);
      u1 = MFMA32(k1, qf[ks], u1);
      __builtin_amdgcn_s_setprio(0);
    }
    s0 = u0; s1 = u1;
  };

  // softmax (fixed-max, raw exp2) + PV over one 64-key sub-tile
  auto smpv64 = [&](f32x16& s0, f32x16& s1, const unsigned short* vtb, int base) {
#pragma unroll
    for (int ks = 0; ks < 4; ++ks) {
      float e[8];
#pragma unroll
      for (int j = 0; j < 8; ++j) {
        float sv = (ks < 2) ? s0[(ks & 1) * 8 + j] : s1[(ks & 1) * 8 + j];
        e[j] = EXPFN(sv);
      }
      l += ((e[0] + e[1]) + (e[2] + e[3])) + ((e[4] + e[5]) + (e[6] + e[7]));
      i32x2 r0 = plswap(cvtpk(e[0], e[1]), cvtpk(e[4], e[5]));
      i32x2 r1 = plswap(cvtpk(e[2], e[3]), cvtpk(e[6], e[7]));
      union { int i[4]; bf16x8 v; } pa;
      pa.i[0] = r0.x; pa.i[1] = r1.x; pa.i[2] = r0.y; pa.i[3] = r1.y;

      bf16x8 v0 = *(const bf16x8*)&vtb[base + ca[ks]];
      bf16x8 v1 = *(const bf16x8*)&vtb[base + cb[ks]];
      __builtin_amdgcn_s_setprio(1);
      o0 = MFMA32(v0, pa.v, o0);
      o1 = MFMA32(v1, pa.v, o1);
      __builtin_amdgcn_s_setprio(0);
    }
  };

  // tile body: two independent sub-tiles
  auto tilec = [&](const unsigned short* ktb, const unsigned short* vtb) {
    f32x16 sA0, sA1, sB0, sB1;
    qk64(ktb, 0,    sA0, sA1);
    qk64(ktb, 4096, sB0, sB1);
    smpv64(sA0, sA1, vtb, 0);
    smpv64(sB0, sB1, vtb, 4096);
  };

  STAGE(0, 0);
  __syncthreads();
  for (int t = 0; t < NT2; t += 2) {
    STAGE(t + 1, 1);                  // t+1 <= 15, always valid
    tilec(kt[0], vt[0]);
    __syncthreads();
    if (t + 2 < NT2) STAGE(t + 2, 0);
    tilec(kt[1], vt[1]);
    __syncthreads();
  }

  // ---- epilogue ----
  l += __shfl_xor(l, 32);
  float rinv = 1.0f / l;
  float* op = Oh + (size_t)q * DMODEL;
#pragma unroll
  for (int r4 = 0; r4 < 4; ++r4) {
    float4 w0, w1;
    w0.x = o0[4 * r4 + 0] * rinv; w0.y = o0[4 * r4 + 1] * rinv;
    w0.z = o0[4 * r4 + 2] * rinv; w0.w = o0[4 * r4 + 3] * rinv;
    w1.x = o1[4 * r4 + 0] * rinv; w1.y = o1[4 * r4 + 1] * rinv;
    w1.z = o1[4 * r4 + 2] * rinv; w1.w = o1[4 * r4 + 3] * rinv;
    *(float4*)(op + 8 * r4 + 4 * hi)      = w0;
    *(float4*)(op + 32 + 8 * r4 + 4 * hi) = w1;
  }
}

extern "C" void kernel_launch(void* const* d_in, const int* in_sizes, int n_in,
                              void* d_out, int out_size, void* d_ws, size_t ws_size,
                              hipStream_t stream) {
  const float* Q = (const float*)d_in[0];
  const float* K = (const float*)d_in[1];
  const float* V = (const float*)d_in[2];
  float* O = (float*)d_out;
  unsigned short* kb = (unsigned short*)d_ws;
  unsigned short* vb = kb + (size_t)32 * SEQ * 64;
  prep_kv<<<3072, 256, 0, stream>>>(K, V, kb, vb);
  fa_fwd<<<256, 512, 0, stream>>>(Q, kb, vb, O);
}